// Round 8
// baseline (396.864 us; speedup 1.0000x reference)
//
#include <hip/hip_runtime.h>
#include <hip/hip_bf16.h>

// Problem constants
#define M_TOT   8192      // B*N tokens
#define D_IN    4096
#define D_OUT   4096
#define N_E     8
#define N_R     16
#define D_ATT   128
#define ER      128       // N_E*N_R
#define CATN    384       // 2*D_ATT + ER
#define KEXT    4224      // D_IN + ER (padded K for unified GEMM)
#define NTK     66        // KEXT/64 K-tiles (even)
#define NW4     (4194304L)  // D_OUT*D_IN/4

typedef __attribute__((ext_vector_type(8)))  __bf16 bf16x8;
typedef __attribute__((ext_vector_type(4)))  float  f32x4;

__device__ __forceinline__ ushort f2bf(float f) {
  union { float f; unsigned u; } v; v.f = f;
  unsigned r = (v.u + 0x7fffu + ((v.u >> 16) & 1u)) >> 16;
  return (ushort)r;
}
__device__ __forceinline__ float bf2f(ushort u) {
  union { unsigned u; float f; } v; v.u = ((unsigned)u) << 16;
  return v.f;
}
__device__ __forceinline__ unsigned cvt_pk(float lo, float hi) {
  unsigned r;
  asm("v_cvt_pk_bf16_f32 %0, %1, %2" : "=v"(r) : "v"(lo), "v"(hi));
  return r;
}

// ---- merged preps: weight fp32->bf16 strided (bulk), rV/rU -> cat rows
// 0..255, expA -> cat rows 256..383, expB -> we cols 4096..  (one launch)
__global__ void prep_all_kernel(const float* __restrict__ wgt,
                                const float* __restrict__ rV, const float* __restrict__ rU,
                                const float* __restrict__ expA, const float* __restrict__ expB,
                                ushort* __restrict__ we, ushort* __restrict__ cat) {
  int b = blockIdx.x;
  if (b < 16384) {                      // weight conversion, float4 granules
    long j = (long)b * 256 + threadIdx.x;         // < NW4
    const float4 a = reinterpret_cast<const float4*>(wgt)[j];
    ushort4 r; r.x = f2bf(a.x); r.y = f2bf(a.y); r.z = f2bf(a.z); r.w = f2bf(a.w);
    long row = j >> 10, c4 = (j & 1023) << 2;
    *reinterpret_cast<ushort4*>(we + row * KEXT + c4) = r;
  } else if (b < 17408) {               // rV (512) + rU (512), float4 elems
    int bb = b - 16384;
    const float* src = (bb < 512) ? rV : rU;
    ushort* dst = cat + ((bb < 512) ? 0 : (size_t)D_ATT * D_IN);
    int i = (bb & 511) * 256 + threadIdx.x;       // < 131072
    const float4 a = reinterpret_cast<const float4*>(src)[i];
    ushort4 r; r.x = f2bf(a.x); r.y = f2bf(a.y); r.z = f2bf(a.z); r.w = f2bf(a.w);
    reinterpret_cast<ushort4*>(dst)[i] = r;
  } else if (b < 19456) {               // catA scatter
    int idx = (b - 17408) * 256 + threadIdx.x;    // < 524288
    int j = idx >> 12, d = idx & 4095;
    int e = j >> 4, r = j & 15;
    cat[(size_t)(2 * D_ATT + j) * D_IN + d] = f2bf(expA[((size_t)e * D_IN + d) * N_R + r]);
  } else {                              // bt transpose
    int idx = (b - 19456) * 256 + threadIdx.x;    // < 524288
    int j = idx >> 12, o = idx & 4095;            // coalesced read of expB row j
    we[(size_t)o * KEXT + D_IN + j] = f2bf(expB[(size_t)j * D_OUT + o]);
  }
}

// ---- gating over split-K partials P[2][M][CATN] (bf16):
// P[*][m,0:128]=xV^T, [128:256]=xU^T, [256:384]=lora_down; writes weighted
// lora-down into x_ext cols 4096..4223 (stride KEXT)
__global__ void gate_kernel(const ushort* __restrict__ P, const float* __restrict__ rW,
                            ushort* __restrict__ wtd) {
  int token = blockIdx.x * 4 + (threadIdx.x >> 6);
  int l = threadIdx.x & 63;
  const ushort* p0 = P + (size_t)token * CATN;
  const ushort* p1 = p0 + (size_t)M_TOT * CATN;
  float v0 = tanhf(bf2f(p0[l])      + bf2f(p1[l]));
  float v1 = tanhf(bf2f(p0[l + 64]) + bf2f(p1[l + 64]));
  float u0 = 1.f / (1.f + __expf(-(bf2f(p0[D_ATT + l])      + bf2f(p1[D_ATT + l]))));
  float u1 = 1.f / (1.f + __expf(-(bf2f(p0[D_ATT + l + 64]) + bf2f(p1[D_ATT + l + 64]))));
  float g0 = v0 * u0, g1 = v1 * u1;
  float rw[8];
  #pragma unroll
  for (int e = 0; e < 8; ++e) {
    float s = g0 * rW[e * D_ATT + l] + g1 * rW[e * D_ATT + l + 64];
    #pragma unroll
    for (int off = 32; off > 0; off >>= 1) s += __shfl_xor(s, off);
    rw[e] = 1.f / (1.f + __expf(-s));
  }
  int q = l >> 4;  // expert index within half (static-select to avoid scratch)
  float rw_a = (q == 0) ? rw[0] : (q == 1) ? rw[1] : (q == 2) ? rw[2] : rw[3];
  float rw_b = (q == 0) ? rw[4] : (q == 1) ? rw[5] : (q == 2) ? rw[6] : rw[7];
  float lo_a = bf2f(p0[2 * D_ATT + l])      + bf2f(p1[2 * D_ATT + l]);
  float lo_b = bf2f(p0[2 * D_ATT + l + 64]) + bf2f(p1[2 * D_ATT + l + 64]);
  wtd[(size_t)token * KEXT + l]      = f2bf(lo_a * rw_a);
  wtd[(size_t)token * KEXT + l + 64] = f2bf(lo_b * rw_b);
}

// ---- 128^2 m97-structure router GEMM with FUSED x conversion, split-K=2 ----
// A-path reads x FP32, converts in-register (v_cvt_pk_bf16_f32), ds_writes the
// same linear LDS layout as before (frag reads/MFMA untouched). bcol==0 blocks
// side-write the converted bf16 tile to xe (each (brow,z) covered once) --
// this replaces the standalone x-conversion pass entirely.
// ds_write bank check: byte = row*128 + (l&7)*16 -> 8 lanes per 16B cluster,
// conflict-free. 3 blocks/CU TLP hides the serial load->cvt->write->sync.
__global__ __launch_bounds__(256, 3)
void gemm128_kernel(const float* __restrict__ X, const ushort* __restrict__ Bm,
                    ushort* __restrict__ C, ushort* __restrict__ xe)
{
  __shared__ ushort As[128 * 64];
  __shared__ ushort Bs[128 * 64];
  const int tid = threadIdx.x;
  const int w = tid >> 6, l = tid & 63;
  const int wr = w >> 1, wc = w & 1;
  const int l16 = l & 15, lq = l >> 4;
  const int brow = blockIdx.y * 128;
  const int bcol = blockIdx.x * 128;
  const int kt0 = (int)blockIdx.z << 5;           // 32 K-tiles per split
  const bool side = (blockIdx.x == 0);

  f32x4 acc[4][4] = {};

  for (int kt = kt0; kt < kt0 + 32; ++kt) {
    int k0 = kt << 6;
    #pragma unroll
    for (int c = 0; c < 4; ++c) {
      int rloc = w * 32 + c * 8;
      int rl = rloc + (l >> 3);
      int kk = k0 + (l & 7) * 8;
      // A: fp32 reg-stage + convert (+ one-time side-write of xe)
      const float* gx = X + (size_t)(brow + rl) * D_IN + kk;
      float4 a0 = *reinterpret_cast<const float4*>(gx);
      float4 a1 = *reinterpret_cast<const float4*>(gx + 4);
      uint4 pk;
      pk.x = cvt_pk(a0.x, a0.y); pk.y = cvt_pk(a0.z, a0.w);
      pk.z = cvt_pk(a1.x, a1.y); pk.w = cvt_pk(a1.z, a1.w);
      *reinterpret_cast<uint4*>(As + (size_t)rl * 64 + (l & 7) * 8) = pk;
      if (side)
        *reinterpret_cast<uint4*>(xe + (size_t)(brow + rl) * KEXT + kk) = pk;
      // B: bf16 async stage (cat is pre-converted, small)
      const ushort* gb = Bm + (size_t)(bcol + rl) * D_IN + kk;
      __builtin_amdgcn_global_load_lds((const __attribute__((address_space(1))) void*)gb,
                                       (__attribute__((address_space(3))) void*)(Bs + rloc * 64),
                                       16, 0, 0);
    }
    __syncthreads();

    #pragma unroll
    for (int ks = 0; ks < 2; ++ks) {
      bf16x8 af[4], bfv[4];
      #pragma unroll
      for (int mi = 0; mi < 4; ++mi)
        af[mi] = *reinterpret_cast<const bf16x8*>(As + (wr * 64 + mi * 16 + l16) * 64 + ks * 32 + lq * 8);
      #pragma unroll
      for (int ni = 0; ni < 4; ++ni)
        bfv[ni] = *reinterpret_cast<const bf16x8*>(Bs + (wc * 64 + ni * 16 + l16) * 64 + ks * 32 + lq * 8);
      #pragma unroll
      for (int mi = 0; mi < 4; ++mi)
        #pragma unroll
        for (int ni = 0; ni < 4; ++ni)
          acc[mi][ni] = __builtin_amdgcn_mfma_f32_16x16x32_bf16(af[mi], bfv[ni], acc[mi][ni], 0, 0, 0);
    }
    __syncthreads();
  }

  ushort* Cz = C + (size_t)blockIdx.z * M_TOT * CATN;
  #pragma unroll
  for (int ni = 0; ni < 4; ++ni) {
    int col = bcol + wc * 64 + ni * 16 + l16;
    #pragma unroll
    for (int mi = 0; mi < 4; ++mi) {
      f32x4 v = acc[mi][ni];
      int row0 = brow + wr * 64 + mi * 16 + lq * 4;
      #pragma unroll
      for (int j = 0; j < 4; ++j)
        Cz[(size_t)(row0 + j) * CATN + col] = f2bf(v[j]);
    }
  }
}

// ---- 256^2 8-phase GEMM with READ ROTATION (R4-proven 16x16 core) ----
// + 2D XCD chunking (R5-proven: FETCH 557->205 MB).  UNCHANGED from R6/R7.
// 8 waves (2M x 4N), BK=64, double-buffered LDS (128 KiB), full 3-bit swizzle
// (elem' = elem ^ ((row&7)<<3); linear LDS dest + inverse-swizzled global src).
// Per tile t (buf=t&1):
//  P1: stage Ah0(t+1); bar; lgkm0[waits R1 from prev P4]; {rd B-hi | MFMA AloxBlo}; bar
//  P2: stage Ah1(t+1); bar; lgkm0[waits B-hi];           {rd A-hi | MFMA AloxBhi}; bar
//  P3: stage Bh0(t+2); bar; lgkm0[waits A-hi];           {        MFMA AhixBhi}; bar
//  P4: stage Bh1(t+2); vmcnt(4); bar;                    {rd R1(t+1) | MFMA AhixBlo}; bar
__global__ __launch_bounds__(512, 2)
void gemm256_kernel(const ushort* __restrict__ A, const ushort* __restrict__ Bm,
                    float* __restrict__ C, const float* __restrict__ bias)
{
  __shared__ ushort lds[2][2][2][8192];   // [buf][mat 0=A 1=B][half][128*64]
  const int tid = threadIdx.x;
  const int wid = tid >> 6, l = tid & 63;
  const int wr = wid >> 2, wc = wid & 3;
  const int l16 = l & 15, lq = l >> 4;
  const int rxor = (l16 & 7) << 3;             // read-side elem XOR (row&7)<<3

  // XCD-aware 2D chunking: 512 blocks = 8 XCDs x 64; each XCD an 8x8 chunk.
  const int xcd = (int)blockIdx.x & 7, q = (int)blockIdx.x >> 3;
  const int brow = ((xcd >> 1) * 8 + (q >> 3)) * 256;
  const int bcol = ((xcd & 1) * 8 + (q & 7)) * 256;

  // staging: linear LDS dest; global source col pre-swizzled by dest row&7
  const int srow = tid >> 3;
  const int scol = (((tid & 7) ^ ((tid >> 3) & 7)) << 3);

#define STAGE(buf_, mat_, half_, kt_) do {                                        \
    const ushort* _s = (mat_) ? Bm : A;                                           \
    int _rb = ((mat_) ? bcol : brow) + (half_) * 128 + srow;                      \
    ushort* _d = &lds[(buf_)][(mat_)][(half_)][wid * 512];                        \
    _Pragma("unroll")                                                             \
    for (int _c = 0; _c < 2; ++_c) {                                              \
      const ushort* _g = _s + (size_t)(_rb + _c * 64) * KEXT + (kt_) * 64 + scol; \
      __builtin_amdgcn_global_load_lds(                                           \
          (const __attribute__((address_space(1))) void*)_g,                      \
          (__attribute__((address_space(3))) void*)(_d + _c * 4096), 16, 0, 0);   \
    } } while (0)

#define LDA_FRAG(buf_, mi_, ks_) \
  (*reinterpret_cast<const bf16x8*>(&lds[(buf_)][0][wr][((mi_) * 16 + l16) * 64 + (((ks_) * 32 + lq * 8) ^ rxor)]))
#define LDB_FRAG(buf_, ni_, ks_) \
  (*reinterpret_cast<const bf16x8*>(&lds[(buf_)][1][wc >> 1][((wc & 1) * 64 + (ni_) * 16 + l16) * 64 + (((ks_) * 32 + lq * 8) ^ rxor)]))

#define RD_ALO(buf_, dst_) \
    _Pragma("unroll") for (int mi = 0; mi < 4; ++mi) \
      _Pragma("unroll") for (int ks = 0; ks < 2; ++ks) dst_[mi][ks] = LDA_FRAG(buf_, mi, ks);
#define RD_BLO(buf_, dst_) \
    _Pragma("unroll") for (int ni = 0; ni < 2; ++ni) \
      _Pragma("unroll") for (int ks = 0; ks < 2; ++ks) dst_[ni][ks] = LDB_FRAG(buf_, ni, ks);

#define MFMA_Q(accm0_, accn0_, a_, b_) \
    _Pragma("unroll") for (int mi = 0; mi < 4; ++mi) \
      _Pragma("unroll") for (int ni = 0; ni < 2; ++ni) \
        _Pragma("unroll") for (int ks = 0; ks < 2; ++ks) \
          acc[(accm0_) + mi][(accn0_) + ni] = __builtin_amdgcn_mfma_f32_16x16x32_bf16( \
              a_[mi][ks], b_[ni][ks], acc[(accm0_) + mi][(accn0_) + ni], 0, 0, 0);

#define TILE(t_, buf_, aIn_, b0In_, aOut_, b0Out_) do {                           \
    bf16x8 b1[2][2], aHi[4][2];                                                   \
    const int ktA = ((t_) + 1 < NTK) ? (t_) + 1 : NTK - 1;                        \
    const int ktB = ((t_) + 2 < NTK) ? (t_) + 2 : NTK - 1;                        \
    /* P1 */                                                                      \
    STAGE(buf_ ^ 1, 0, 0, ktA);                                                   \
    __builtin_amdgcn_s_barrier();                                                 \
    asm volatile("s_waitcnt lgkmcnt(0)" ::: "memory");                            \
    __builtin_amdgcn_s_setprio(1);                                                \
    _Pragma("unroll") for (int ni = 0; ni < 2; ++ni)                              \
      _Pragma("unroll") for (int ks = 0; ks < 2; ++ks)                            \
        b1[ni][ks] = LDB_FRAG(buf_, ni + 2, ks);                                  \
    MFMA_Q(0, 0, aIn_, b0In_);                                                    \
    __builtin_amdgcn_s_setprio(0);                                                \
    __builtin_amdgcn_s_barrier();                                                 \
    /* P2 */                                                                      \
    STAGE(buf_ ^ 1, 0, 1, ktA);                                                   \
    __builtin_amdgcn_s_barrier();                                                 \
    asm volatile("s_waitcnt lgkmcnt(0)" ::: "memory");                            \
    __builtin_amdgcn_s_setprio(1);                                                \
    _Pragma("unroll") for (int mi = 0; mi < 4; ++mi)                              \
      _Pragma("unroll") for (int ks = 0; ks < 2; ++ks)                            \
        aHi[mi][ks] = LDA_FRAG(buf_, mi + 4, ks);                                 \
    MFMA_Q(0, 2, aIn_, b1);                                                       \
    __builtin_amdgcn_s_setprio(0);                                                \
    __builtin_amdgcn_s_barrier();                                                 \
    /* P3 */                                                                      \
    STAGE(buf_, 1, 0, ktB);                                                       \
    __builtin_amdgcn_s_barrier();                                                 \
    asm volatile("s_waitcnt lgkmcnt(0)" ::: "memory");                            \
    __builtin_amdgcn_s_setprio(1);                                                \
    MFMA_Q(4, 2, aHi, b1);                                                        \
    __builtin_amdgcn_s_setprio(0);                                                \
    __builtin_amdgcn_s_barrier();                                                 \
    /* P4 */                                                                      \
    STAGE(buf_, 1, 1, ktB);                                                       \
    asm volatile("s_waitcnt vmcnt(4)" ::: "memory");                              \
    __builtin_amdgcn_s_barrier();                                                 \
    __builtin_amdgcn_s_setprio(1);                                                \
    RD_ALO(buf_ ^ 1, aOut_);                                                      \
    RD_BLO(buf_ ^ 1, b0Out_);                                                     \
    MFMA_Q(4, 0, aHi, b0In_);                                                     \
    __builtin_amdgcn_s_setprio(0);                                                \
    __builtin_amdgcn_s_barrier();                                                 \
  } while (0)

  f32x4 acc[8][4] = {};
  bf16x8 aA[4][2], b0A[2][2], aB[4][2], b0B[2][2];

  // prologue: tile 0 complete + B(1); leave B(1) in flight, then pre-read R1(0)
  STAGE(0, 0, 0, 0); STAGE(0, 0, 1, 0);
  STAGE(0, 1, 0, 0); STAGE(0, 1, 1, 0);
  STAGE(1, 1, 0, 1); STAGE(1, 1, 1, 1);
  asm volatile("s_waitcnt vmcnt(4)" ::: "memory");
  __builtin_amdgcn_s_barrier();
  RD_ALO(0, aA);
  RD_BLO(0, b0A);

  #pragma unroll 1
  for (int tp = 0; tp < NTK / 2; ++tp) {
    TILE(2 * tp,     0, aA, b0A, aB, b0B);
    TILE(2 * tp + 1, 1, aB, b0B, aA, b0A);
  }

  asm volatile("s_waitcnt vmcnt(0) lgkmcnt(0)" ::: "memory");

  // epilogue: C/D layout col=l&15, row=(l>>4)*4+j (m89-verified)
  #pragma unroll
  for (int ni = 0; ni < 4; ++ni) {
    int col = bcol + wc * 64 + ni * 16 + l16;
    float bs = bias[col];
    #pragma unroll
    for (int mi = 0; mi < 8; ++mi) {
      int row0 = brow + wr * 128 + mi * 16 + lq * 4;
      #pragma unroll
      for (int j = 0; j < 4; ++j)
        C[(size_t)(row0 + j) * D_OUT + col] = acc[mi][ni][j] + bs;
    }
  }
#undef STAGE
#undef LDA_FRAG
#undef LDB_FRAG
#undef RD_ALO
#undef RD_BLO
#undef MFMA_Q
#undef TILE
}

extern "C" void kernel_launch(void* const* d_in, const int* in_sizes, int n_in,
                              void* d_out, int out_size, void* d_ws, size_t ws_size,
                              hipStream_t stream) {
  const float* x      = (const float*)d_in[0];
  const float* weight = (const float*)d_in[1];
  const float* bias   = (const float*)d_in[2];
  const float* rV     = (const float*)d_in[3];
  const float* rU     = (const float*)d_in[4];
  const float* rW     = (const float*)d_in[5];
  const float* expA   = (const float*)d_in[6];
  const float* expB   = (const float*)d_in[7];
  float* out = (float*)d_out;

  // workspace: x_ext[8192][4224], w_ext[4096][4224], cat[384][4096],
  // P[2][8192][384] bf16 split-K partials  (total ~119.5 MB, same as R2-R7)
  ushort* xe  = (ushort*)d_ws;
  ushort* we  = xe  + (size_t)M_TOT * KEXT;
  ushort* cat = we  + (size_t)D_OUT * KEXT;
  ushort* P   = cat + (size_t)CATN * D_IN;

  // weight conversion + all small preps (one launch; x conversion is fused
  // into gemm128's staging)
  prep_all_kernel<<<dim3(16384 + 1024 + 2048 + 2048), 256, 0, stream>>>(
      weight, rV, rU, expA, expB, we, cat);

  // P[z] = x @ Cat^T partials (fp32 A, fused convert); bcol==0 writes xe
  gemm128_kernel<<<dim3(CATN / 128, M_TOT / 128, 2), 256, 0, stream>>>(x, cat, P, xe);

  // weighted lora-down -> x_ext cols 4096..4223
  gate_kernel<<<dim3(M_TOT / 4), 256, 0, stream>>>(P, rW, xe + D_IN);

  // out = x_ext @ w_ext^T + bias   [8192, 4096], K = 4224
  gemm256_kernel<<<dim3((D_OUT / 256) * (M_TOT / 256)), 512, 0, stream>>>(xe, we, out, bias);
}

// Round 9
// 348.292 us; speedup vs baseline: 1.1395x; 1.1395x over previous
//
#include <hip/hip_runtime.h>
#include <hip/hip_bf16.h>

// Problem constants
#define M_TOT   8192      // B*N tokens
#define D_IN    4096
#define D_OUT   4096
#define N_E     8
#define N_R     16
#define D_ATT   128
#define ER      128       // N_E*N_R
#define CATN    384       // 2*D_ATT + ER
#define KEXT    4224      // D_IN + ER (padded K for unified GEMM)
#define NTK     66        // KEXT/64 K-tiles (even)
#define NX4     (8388608L)  // M_TOT*D_IN/4
#define NW4     (4194304L)  // D_OUT*D_IN/4

typedef __attribute__((ext_vector_type(8)))  __bf16 bf16x8;
typedef __attribute__((ext_vector_type(4)))  float  f32x4;

__device__ __forceinline__ ushort f2bf(float f) {
  union { float f; unsigned u; } v; v.f = f;
  unsigned r = (v.u + 0x7fffu + ((v.u >> 16) & 1u)) >> 16;
  return (ushort)r;
}
__device__ __forceinline__ float bf2f(ushort u) {
  union { unsigned u; float f; } v; v.u = ((unsigned)u) << 16;
  return v.f;
}

// ---- merged fp32->bf16 conversion of x and weight into strided [*][KEXT] ----
__global__ void conv_xw_kernel(const float* __restrict__ x, const float* __restrict__ w,
                               ushort* __restrict__ xe, ushort* __restrict__ we) {
  long i = blockIdx.x * (long)blockDim.x + threadIdx.x;  // grid exact: NX4+NW4
  const float* src; ushort* dst; long j;
  if (i < NX4) { src = x; dst = xe; j = i; }
  else         { src = w; dst = we; j = i - NX4; }
  const float4 a = reinterpret_cast<const float4*>(src)[j];
  ushort4 r; r.x = f2bf(a.x); r.y = f2bf(a.y); r.z = f2bf(a.z); r.w = f2bf(a.w);
  long row = j >> 10, c4 = (j & 1023) << 2;
  *reinterpret_cast<ushort4*>(dst + row * KEXT + c4) = r;
}

// ---- merged small preps: rV/rU -> cat rows 0..255 (float4 conv),
// expA -> cat rows 256..383 (Cat[256+e*16+r][d] = expA[e][d][r]),
// expB -> we cols 4096.. (we[o][4096+j] = expB[j][o]).  5120 blocks total.
__global__ void prep_small_kernel(const float* __restrict__ rV, const float* __restrict__ rU,
                                  const float* __restrict__ expA, const float* __restrict__ expB,
                                  ushort* __restrict__ cat, ushort* __restrict__ we) {
  int b = blockIdx.x;
  if (b < 1024) {                       // rV (512) + rU (512), float4 elems
    const float* src = (b < 512) ? rV : rU;
    ushort* dst = cat + ((b < 512) ? 0 : (size_t)D_ATT * D_IN);
    int i = (b & 511) * 256 + threadIdx.x;          // < 131072
    const float4 a = reinterpret_cast<const float4*>(src)[i];
    ushort4 r; r.x = f2bf(a.x); r.y = f2bf(a.y); r.z = f2bf(a.z); r.w = f2bf(a.w);
    reinterpret_cast<ushort4*>(dst)[i] = r;
  } else if (b < 3072) {                // catA scatter
    int idx = (b - 1024) * 256 + threadIdx.x;       // < 524288
    int j = idx >> 12, d = idx & 4095;
    int e = j >> 4, r = j & 15;
    cat[(size_t)(2 * D_ATT + j) * D_IN + d] = f2bf(expA[((size_t)e * D_IN + d) * N_R + r]);
  } else {                              // bt transpose
    int idx = (b - 3072) * 256 + threadIdx.x;       // < 524288
    int j = idx >> 12, o = idx & 4095;              // coalesced read of expB row j
    we[(size_t)o * KEXT + D_IN + j] = f2bf(expB[(size_t)j * D_OUT + o]);
  }
}

// ---- gating over split-K partials P[2][M][CATN] (bf16):
// P[*][m,0:128]=xV^T, [128:256]=xU^T, [256:384]=lora_down; writes weighted
// lora-down into x_ext cols 4096..4223 (stride KEXT)
__global__ void gate_kernel(const ushort* __restrict__ P, const float* __restrict__ rW,
                            ushort* __restrict__ wtd) {
  int token = blockIdx.x * 4 + (threadIdx.x >> 6);
  int l = threadIdx.x & 63;
  const ushort* p0 = P + (size_t)token * CATN;
  const ushort* p1 = p0 + (size_t)M_TOT * CATN;
  float v0 = tanhf(bf2f(p0[l])      + bf2f(p1[l]));
  float v1 = tanhf(bf2f(p0[l + 64]) + bf2f(p1[l + 64]));
  float u0 = 1.f / (1.f + __expf(-(bf2f(p0[D_ATT + l])      + bf2f(p1[D_ATT + l]))));
  float u1 = 1.f / (1.f + __expf(-(bf2f(p0[D_ATT + l + 64]) + bf2f(p1[D_ATT + l + 64]))));
  float g0 = v0 * u0, g1 = v1 * u1;
  float rw[8];
  #pragma unroll
  for (int e = 0; e < 8; ++e) {
    float s = g0 * rW[e * D_ATT + l] + g1 * rW[e * D_ATT + l + 64];
    #pragma unroll
    for (int off = 32; off > 0; off >>= 1) s += __shfl_xor(s, off);
    rw[e] = 1.f / (1.f + __expf(-s));
  }
  int q = l >> 4;  // expert index within half (static-select to avoid scratch)
  float rw_a = (q == 0) ? rw[0] : (q == 1) ? rw[1] : (q == 2) ? rw[2] : rw[3];
  float rw_b = (q == 0) ? rw[4] : (q == 1) ? rw[5] : (q == 2) ? rw[6] : rw[7];
  float lo_a = bf2f(p0[2 * D_ATT + l])      + bf2f(p1[2 * D_ATT + l]);
  float lo_b = bf2f(p0[2 * D_ATT + l + 64]) + bf2f(p1[2 * D_ATT + l + 64]);
  wtd[(size_t)token * KEXT + l]      = f2bf(lo_a * rw_a);
  wtd[(size_t)token * KEXT + l + 64] = f2bf(lo_b * rw_b);
}

// ---- 128^2 m97-structure router GEMM, split-K=2 (R7-proven version) ----
// P[z] = x_ext[:, z*2048:(z+1)*2048] @ cat[:, same]^T  (bf16 partials)
__global__ __launch_bounds__(256, 4)
void gemm128_kernel(const ushort* __restrict__ A, const ushort* __restrict__ Bm,
                    ushort* __restrict__ C)
{
  __shared__ ushort As[128 * 64];
  __shared__ ushort Bs[128 * 64];
  const int tid = threadIdx.x;
  const int w = tid >> 6, l = tid & 63;
  const int wr = w >> 1, wc = w & 1;
  const int l16 = l & 15, lq = l >> 4;
  const int brow = blockIdx.y * 128;
  const int bcol = blockIdx.x * 128;
  const int kt0 = (int)blockIdx.z << 5;           // 32 K-tiles per split

  f32x4 acc[4][4] = {};

  for (int kt = kt0; kt < kt0 + 32; ++kt) {
    int k0 = kt << 6;
    #pragma unroll
    for (int c = 0; c < 4; ++c) {
      int rloc = w * 32 + c * 8;
      int rl = rloc + (l >> 3);
      int kk = k0 + (l & 7) * 8;
      const ushort* ga = A  + (size_t)(brow + rl) * KEXT + kk;
      const ushort* gb = Bm + (size_t)(bcol + rl) * D_IN + kk;
      __builtin_amdgcn_global_load_lds((const __attribute__((address_space(1))) void*)ga,
                                       (__attribute__((address_space(3))) void*)(As + rloc * 64),
                                       16, 0, 0);
      __builtin_amdgcn_global_load_lds((const __attribute__((address_space(1))) void*)gb,
                                       (__attribute__((address_space(3))) void*)(Bs + rloc * 64),
                                       16, 0, 0);
    }
    __syncthreads();

    #pragma unroll
    for (int ks = 0; ks < 2; ++ks) {
      bf16x8 af[4], bfv[4];
      #pragma unroll
      for (int mi = 0; mi < 4; ++mi)
        af[mi] = *reinterpret_cast<const bf16x8*>(As + (wr * 64 + mi * 16 + l16) * 64 + ks * 32 + lq * 8);
      #pragma unroll
      for (int ni = 0; ni < 4; ++ni)
        bfv[ni] = *reinterpret_cast<const bf16x8*>(Bs + (wc * 64 + ni * 16 + l16) * 64 + ks * 32 + lq * 8);
      #pragma unroll
      for (int mi = 0; mi < 4; ++mi)
        #pragma unroll
        for (int ni = 0; ni < 4; ++ni)
          acc[mi][ni] = __builtin_amdgcn_mfma_f32_16x16x32_bf16(af[mi], bfv[ni], acc[mi][ni], 0, 0, 0);
    }
    __syncthreads();
  }

  ushort* Cz = C + (size_t)blockIdx.z * M_TOT * CATN;
  #pragma unroll
  for (int ni = 0; ni < 4; ++ni) {
    int col = bcol + wc * 64 + ni * 16 + l16;
    #pragma unroll
    for (int mi = 0; mi < 4; ++mi) {
      f32x4 v = acc[mi][ni];
      int row0 = brow + wr * 64 + mi * 16 + lq * 4;
      #pragma unroll
      for (int j = 0; j < 4; ++j)
        Cz[(size_t)(row0 + j) * CATN + col] = f2bf(v[j]);
    }
  }
}

// ---- 256^2 GEMM, 2-PHASE tiles (merged from 4): out = x_ext @ w_ext^T + bias ----
// 8 waves (2M x 4N), BK=64, double-buffered LDS (128 KiB), full 3-bit swizzle,
// 2D XCD chunking (R5-proven). Per tile t (buf=t&1), 4 barriers (was 8):
//  PA: STAGE A(t+1) h0+h1; bar; lgkm0[waits PB(t-1) reads];
//      {rd aHi(t) | 32 MFMA: aLo x (bLo,bHi)}; bar
//  PB: STAGE B(t+2) h0+h1; vmcnt(4)[A(t+1),B(t+1) landed; B(t+2) in flight];
//      bar; lgkm0[waits aHi];
//      {rd aLo(t+1)+b(t+1) | 32 MFMA: aHi x (bLo,bHi)}; bar
// Longer 32-MFMA windows (~155cy) cover the frag-read latency that the 16-MFMA
// windows (~78cy) could not; half the barrier skews. Clobber safety: A(t+1)
// overwrite vs A(t-1) reads and B(t+2) vs B(t) reads are both barrier-separated
// (reads complete at the preceding lgkm0, all waves pass the end-bar).
__global__ __launch_bounds__(512, 1)
void gemm256_kernel(const ushort* __restrict__ A, const ushort* __restrict__ Bm,
                    float* __restrict__ C, const float* __restrict__ bias)
{
  __shared__ ushort lds[2][2][2][8192];   // [buf][mat 0=A 1=B][half][128*64]
  const int tid = threadIdx.x;
  const int wid = tid >> 6, l = tid & 63;
  const int wr = wid >> 2, wc = wid & 3;
  const int l16 = l & 15, lq = l >> 4;
  const int rxor = (l16 & 7) << 3;             // read-side elem XOR (row&7)<<3

  // XCD-aware 2D chunking: 512 blocks = 8 XCDs x 64; each XCD an 8x8 chunk.
  const int xcd = (int)blockIdx.x & 7, q = (int)blockIdx.x >> 3;
  const int brow = ((xcd >> 1) * 8 + (q >> 3)) * 256;
  const int bcol = ((xcd & 1) * 8 + (q & 7)) * 256;

  // staging: linear LDS dest; global source col pre-swizzled by dest row&7
  const int srow = tid >> 3;
  const int scol = (((tid & 7) ^ ((tid >> 3) & 7)) << 3);

#define STAGE(buf_, mat_, half_, kt_) do {                                        \
    const ushort* _s = (mat_) ? Bm : A;                                           \
    int _rb = ((mat_) ? bcol : brow) + (half_) * 128 + srow;                      \
    ushort* _d = &lds[(buf_)][(mat_)][(half_)][wid * 512];                        \
    _Pragma("unroll")                                                             \
    for (int _c = 0; _c < 2; ++_c) {                                              \
      const ushort* _g = _s + (size_t)(_rb + _c * 64) * KEXT + (kt_) * 64 + scol; \
      __builtin_amdgcn_global_load_lds(                                           \
          (const __attribute__((address_space(1))) void*)_g,                      \
          (__attribute__((address_space(3))) void*)(_d + _c * 4096), 16, 0, 0);   \
    } } while (0)

#define LDA_FRAG(buf_, mi_, ks_) \
  (*reinterpret_cast<const bf16x8*>(&lds[(buf_)][0][wr][((mi_) * 16 + l16) * 64 + (((ks_) * 32 + lq * 8) ^ rxor)]))
#define LDB_FRAG(buf_, ni_, ks_) \
  (*reinterpret_cast<const bf16x8*>(&lds[(buf_)][1][wc >> 1][((wc & 1) * 64 + (ni_) * 16 + l16) * 64 + (((ks_) * 32 + lq * 8) ^ rxor)]))

#define RD_ALO(buf_, dst_) \
    _Pragma("unroll") for (int mi = 0; mi < 4; ++mi) \
      _Pragma("unroll") for (int ks = 0; ks < 2; ++ks) dst_[mi][ks] = LDA_FRAG(buf_, mi, ks);
#define RD_AHI(buf_, dst_) \
    _Pragma("unroll") for (int mi = 0; mi < 4; ++mi) \
      _Pragma("unroll") for (int ks = 0; ks < 2; ++ks) dst_[mi][ks] = LDA_FRAG(buf_, mi + 4, ks);
#define RD_BALL(buf_, dst_) \
    _Pragma("unroll") for (int ni = 0; ni < 4; ++ni) \
      _Pragma("unroll") for (int ks = 0; ks < 2; ++ks) dst_[ni][ks] = LDB_FRAG(buf_, ni, ks);

#define MFMA_H(accm0_, a_, b_) \
    _Pragma("unroll") for (int mi = 0; mi < 4; ++mi) \
      _Pragma("unroll") for (int ni = 0; ni < 4; ++ni) \
        _Pragma("unroll") for (int ks = 0; ks < 2; ++ks) \
          acc[(accm0_) + mi][ni] = __builtin_amdgcn_mfma_f32_16x16x32_bf16( \
              a_[mi][ks], b_[ni][ks], acc[(accm0_) + mi][ni], 0, 0, 0);

#define TILE2(t_, buf_, aIn_, bIn_, aOut_, bOut_) do {                            \
    bf16x8 aHi[4][2];                                                             \
    const int ktA = ((t_) + 1 < NTK) ? (t_) + 1 : NTK - 1;                        \
    const int ktB = ((t_) + 2 < NTK) ? (t_) + 2 : NTK - 1;                        \
    /* PA */                                                                      \
    STAGE(buf_ ^ 1, 0, 0, ktA);                                                   \
    STAGE(buf_ ^ 1, 0, 1, ktA);                                                   \
    __builtin_amdgcn_s_barrier();                                                 \
    asm volatile("s_waitcnt lgkmcnt(0)" ::: "memory");                            \
    __builtin_amdgcn_s_setprio(1);                                                \
    RD_AHI(buf_, aHi);                                                            \
    MFMA_H(0, aIn_, bIn_);                                                        \
    __builtin_amdgcn_s_setprio(0);                                                \
    __builtin_amdgcn_s_barrier();                                                 \
    /* PB */                                                                      \
    STAGE(buf_, 1, 0, ktB);                                                       \
    STAGE(buf_, 1, 1, ktB);                                                       \
    asm volatile("s_waitcnt vmcnt(4)" ::: "memory");                              \
    __builtin_amdgcn_s_barrier();                                                 \
    asm volatile("s_waitcnt lgkmcnt(0)" ::: "memory");                            \
    __builtin_amdgcn_s_setprio(1);                                                \
    RD_ALO(buf_ ^ 1, aOut_);                                                      \
    RD_BALL(buf_ ^ 1, bOut_);                                                     \
    MFMA_H(4, aHi, bIn_);                                                         \
    __builtin_amdgcn_s_setprio(0);                                                \
    __builtin_amdgcn_s_barrier();                                                 \
  } while (0)

  f32x4 acc[8][4] = {};
  bf16x8 aA[4][2], bA[4][2], aB[4][2], bB[4][2];

  // prologue: tile 0 A+B staged, B(1) staged (stays in flight through vmcnt(4));
  // then pre-read tile-0 aLo + b (the "PB(-1)" rotation reads).
  STAGE(0, 0, 0, 0); STAGE(0, 0, 1, 0);
  STAGE(0, 1, 0, 0); STAGE(0, 1, 1, 0);
  STAGE(1, 1, 0, 1); STAGE(1, 1, 1, 1);
  asm volatile("s_waitcnt vmcnt(4)" ::: "memory");
  __builtin_amdgcn_s_barrier();
  RD_ALO(0, aA);
  RD_BALL(0, bA);

  #pragma unroll 1
  for (int tp = 0; tp < NTK / 2; ++tp) {
    TILE2(2 * tp,     0, aA, bA, aB, bB);
    TILE2(2 * tp + 1, 1, aB, bB, aA, bA);
  }

  asm volatile("s_waitcnt vmcnt(0) lgkmcnt(0)" ::: "memory");

  // epilogue: C/D layout col=l&15, row=(l>>4)*4+j (m89-verified)
  #pragma unroll
  for (int ni = 0; ni < 4; ++ni) {
    int col = bcol + wc * 64 + ni * 16 + l16;
    float bs = bias[col];
    #pragma unroll
    for (int mi = 0; mi < 8; ++mi) {
      int row0 = brow + wr * 128 + mi * 16 + lq * 4;
      #pragma unroll
      for (int j = 0; j < 4; ++j)
        C[(size_t)(row0 + j) * D_OUT + col] = acc[mi][ni][j] + bs;
    }
  }
#undef STAGE
#undef LDA_FRAG
#undef LDB_FRAG
#undef RD_ALO
#undef RD_AHI
#undef RD_BALL
#undef MFMA_H
#undef TILE2
}

extern "C" void kernel_launch(void* const* d_in, const int* in_sizes, int n_in,
                              void* d_out, int out_size, void* d_ws, size_t ws_size,
                              hipStream_t stream) {
  const float* x      = (const float*)d_in[0];
  const float* weight = (const float*)d_in[1];
  const float* bias   = (const float*)d_in[2];
  const float* rV     = (const float*)d_in[3];
  const float* rU     = (const float*)d_in[4];
  const float* rW     = (const float*)d_in[5];
  const float* expA   = (const float*)d_in[6];
  const float* expB   = (const float*)d_in[7];
  float* out = (float*)d_out;

  // workspace: x_ext[8192][4224], w_ext[4096][4224], cat[384][4096],
  // P[2][8192][384] bf16 split-K partials  (total ~119.5 MB, same as R2-R8)
  ushort* xe  = (ushort*)d_ws;
  ushort* we  = xe  + (size_t)M_TOT * KEXT;
  ushort* cat = we  + (size_t)D_OUT * KEXT;
  ushort* P   = cat + (size_t)CATN * D_IN;

  // x + weight -> bf16 strided  (one launch, grid exact)
  conv_xw_kernel<<<dim3((NX4 + NW4) / 256), 256, 0, stream>>>(x, weight, xe, we);

  // rV/rU/expA/expB preps (one launch)
  prep_small_kernel<<<dim3(5120), 256, 0, stream>>>(rV, rU, expA, expB, cat, we);

  // P[z] = x @ Cat^T partials   [2][8192, 384], split-K=2
  gemm128_kernel<<<dim3(CATN / 128, M_TOT / 128, 2), 256, 0, stream>>>(xe, cat, P);

  // weighted lora-down -> x_ext cols 4096..4223
  gate_kernel<<<dim3(M_TOT / 4), 256, 0, stream>>>(P, rW, xe + D_IN);

  // out = x_ext @ w_ext^T + bias   [8192, 4096], K = 4224
  gemm256_kernel<<<dim3((D_OUT / 256) * (M_TOT / 256)), 512, 0, stream>>>(xe, we, out, bias);
}

// Round 10
// 345.484 us; speedup vs baseline: 1.1487x; 1.0081x over previous
//
#include <hip/hip_runtime.h>
#include <hip/hip_bf16.h>

// Problem constants
#define M_TOT   8192      // B*N tokens
#define D_IN    4096
#define D_OUT   4096
#define N_E     8
#define N_R     16
#define D_ATT   128
#define ER      128       // N_E*N_R
#define CATN    384       // 2*D_ATT + ER
#define KEXT    4224      // D_IN + ER (padded K for unified GEMM)
#define NTK     66        // KEXT/64 K-tiles (even)
#define NX4     (8388608L)  // M_TOT*D_IN/4
#define NW4     (4194304L)  // D_OUT*D_IN/4

typedef __attribute__((ext_vector_type(8)))  __bf16 bf16x8;
typedef __attribute__((ext_vector_type(4)))  float  f32x4;

__device__ __forceinline__ ushort f2bf(float f) {
  union { float f; unsigned u; } v; v.f = f;
  unsigned r = (v.u + 0x7fffu + ((v.u >> 16) & 1u)) >> 16;
  return (ushort)r;
}
__device__ __forceinline__ float bf2f(ushort u) {
  union { unsigned u; float f; } v; v.u = ((unsigned)u) << 16;
  return v.f;
}

// ---- merged fp32->bf16 conversion of x and weight into strided [*][KEXT] ----
__global__ void conv_xw_kernel(const float* __restrict__ x, const float* __restrict__ w,
                               ushort* __restrict__ xe, ushort* __restrict__ we) {
  long i = blockIdx.x * (long)blockDim.x + threadIdx.x;  // grid exact: NX4+NW4
  const float* src; ushort* dst; long j;
  if (i < NX4) { src = x; dst = xe; j = i; }
  else         { src = w; dst = we; j = i - NX4; }
  const float4 a = reinterpret_cast<const float4*>(src)[j];
  ushort4 r; r.x = f2bf(a.x); r.y = f2bf(a.y); r.z = f2bf(a.z); r.w = f2bf(a.w);
  long row = j >> 10, c4 = (j & 1023) << 2;
  *reinterpret_cast<ushort4*>(dst + row * KEXT + c4) = r;
}

// ---- merged small preps: rV/rU -> cat rows 0..255 (float4 conv),
// expA -> cat rows 256..383 (Cat[256+e*16+r][d] = expA[e][d][r]),
// expB -> we cols 4096.. (we[o][4096+j] = expB[j][o]).  5120 blocks total.
__global__ void prep_small_kernel(const float* __restrict__ rV, const float* __restrict__ rU,
                                  const float* __restrict__ expA, const float* __restrict__ expB,
                                  ushort* __restrict__ cat, ushort* __restrict__ we) {
  int b = blockIdx.x;
  if (b < 1024) {                       // rV (512) + rU (512), float4 elems
    const float* src = (b < 512) ? rV : rU;
    ushort* dst = cat + ((b < 512) ? 0 : (size_t)D_ATT * D_IN);
    int i = (b & 511) * 256 + threadIdx.x;          // < 131072
    const float4 a = reinterpret_cast<const float4*>(src)[i];
    ushort4 r; r.x = f2bf(a.x); r.y = f2bf(a.y); r.z = f2bf(a.z); r.w = f2bf(a.w);
    reinterpret_cast<ushort4*>(dst)[i] = r;
  } else if (b < 3072) {                // catA scatter
    int idx = (b - 1024) * 256 + threadIdx.x;       // < 524288
    int j = idx >> 12, d = idx & 4095;
    int e = j >> 4, r = j & 15;
    cat[(size_t)(2 * D_ATT + j) * D_IN + d] = f2bf(expA[((size_t)e * D_IN + d) * N_R + r]);
  } else {                              // bt transpose
    int idx = (b - 3072) * 256 + threadIdx.x;       // < 524288
    int j = idx >> 12, o = idx & 4095;              // coalesced read of expB row j
    we[(size_t)o * KEXT + D_IN + j] = f2bf(expB[(size_t)j * D_OUT + o]);
  }
}

// ---- gating over split-K partials P[2][M][CATN] (bf16):
// P[*][m,0:128]=xV^T, [128:256]=xU^T, [256:384]=lora_down; writes weighted
// lora-down into x_ext cols 4096..4223 (stride KEXT)
__global__ void gate_kernel(const ushort* __restrict__ P, const float* __restrict__ rW,
                            ushort* __restrict__ wtd) {
  int token = blockIdx.x * 4 + (threadIdx.x >> 6);
  int l = threadIdx.x & 63;
  const ushort* p0 = P + (size_t)token * CATN;
  const ushort* p1 = p0 + (size_t)M_TOT * CATN;
  float v0 = tanhf(bf2f(p0[l])      + bf2f(p1[l]));
  float v1 = tanhf(bf2f(p0[l + 64]) + bf2f(p1[l + 64]));
  float u0 = 1.f / (1.f + __expf(-(bf2f(p0[D_ATT + l])      + bf2f(p1[D_ATT + l]))));
  float u1 = 1.f / (1.f + __expf(-(bf2f(p0[D_ATT + l + 64]) + bf2f(p1[D_ATT + l + 64]))));
  float g0 = v0 * u0, g1 = v1 * u1;
  float rw[8];
  #pragma unroll
  for (int e = 0; e < 8; ++e) {
    float s = g0 * rW[e * D_ATT + l] + g1 * rW[e * D_ATT + l + 64];
    #pragma unroll
    for (int off = 32; off > 0; off >>= 1) s += __shfl_xor(s, off);
    rw[e] = 1.f / (1.f + __expf(-s));
  }
  int q = l >> 4;  // expert index within half (static-select to avoid scratch)
  float rw_a = (q == 0) ? rw[0] : (q == 1) ? rw[1] : (q == 2) ? rw[2] : rw[3];
  float rw_b = (q == 0) ? rw[4] : (q == 1) ? rw[5] : (q == 2) ? rw[6] : rw[7];
  float lo_a = bf2f(p0[2 * D_ATT + l])      + bf2f(p1[2 * D_ATT + l]);
  float lo_b = bf2f(p0[2 * D_ATT + l + 64]) + bf2f(p1[2 * D_ATT + l + 64]);
  wtd[(size_t)token * KEXT + l]      = f2bf(lo_a * rw_a);
  wtd[(size_t)token * KEXT + l + 64] = f2bf(lo_b * rw_b);
}

// ---- 128^2 m97-structure router GEMM, split-K=2, XCD-grouped dispatch ----
// P[z] = x_ext[:, z*2048:(z+1)*2048] @ cat[:, same]^T  (bf16 partials)
// The 3 bcol-blocks sharing one (brow,z) A-panel get dispatch indices equal
// mod 8 -> same XCD (round-robin) at adjacent slots -> A fetched once to that
// XCD's L2, served 2x from L2 (A-HBM-traffic 192->~80 MB). Bijective decode:
// i in [0,384): xcd=i&7, s=i>>3, bcol=s%3, pair=xcd*16+s/3 -> (brow,z).
__global__ __launch_bounds__(256, 4)
void gemm128_kernel(const ushort* __restrict__ A, const ushort* __restrict__ Bm,
                    ushort* __restrict__ C)
{
  const int tid = threadIdx.x;
  const int w = tid >> 6, l = tid & 63;
  const int wr = w >> 1, wc = w & 1;
  const int l16 = l & 15, lq = l >> 4;

  const int i = (int)blockIdx.x;
  const int xcd = i & 7, s = i >> 3;
  const int bcol = (s % 3) * 128;
  const int pair = xcd * 16 + s / 3;       // [0,128)
  const int brow = (pair >> 1) * 128;
  const int zidx = pair & 1;
  const int kt0 = zidx << 5;               // 32 K-tiles per split

  __shared__ ushort As[128 * 64];
  __shared__ ushort Bs[128 * 64];

  f32x4 acc[4][4] = {};

  for (int kt = kt0; kt < kt0 + 32; ++kt) {
    int k0 = kt << 6;
    #pragma unroll
    for (int c = 0; c < 4; ++c) {
      int rloc = w * 32 + c * 8;
      int rl = rloc + (l >> 3);
      int kk = k0 + (l & 7) * 8;
      const ushort* ga = A  + (size_t)(brow + rl) * KEXT + kk;
      const ushort* gb = Bm + (size_t)(bcol + rl) * D_IN + kk;
      __builtin_amdgcn_global_load_lds((const __attribute__((address_space(1))) void*)ga,
                                       (__attribute__((address_space(3))) void*)(As + rloc * 64),
                                       16, 0, 0);
      __builtin_amdgcn_global_load_lds((const __attribute__((address_space(1))) void*)gb,
                                       (__attribute__((address_space(3))) void*)(Bs + rloc * 64),
                                       16, 0, 0);
    }
    __syncthreads();

    #pragma unroll
    for (int ks = 0; ks < 2; ++ks) {
      bf16x8 af[4], bfv[4];
      #pragma unroll
      for (int mi = 0; mi < 4; ++mi)
        af[mi] = *reinterpret_cast<const bf16x8*>(As + (wr * 64 + mi * 16 + l16) * 64 + ks * 32 + lq * 8);
      #pragma unroll
      for (int ni = 0; ni < 4; ++ni)
        bfv[ni] = *reinterpret_cast<const bf16x8*>(Bs + (wc * 64 + ni * 16 + l16) * 64 + ks * 32 + lq * 8);
      #pragma unroll
      for (int mi = 0; mi < 4; ++mi)
        #pragma unroll
        for (int ni = 0; ni < 4; ++ni)
          acc[mi][ni] = __builtin_amdgcn_mfma_f32_16x16x32_bf16(af[mi], bfv[ni], acc[mi][ni], 0, 0, 0);
    }
    __syncthreads();
  }

  ushort* Cz = C + (size_t)zidx * M_TOT * CATN;
  #pragma unroll
  for (int ni = 0; ni < 4; ++ni) {
    int col = bcol + wc * 64 + ni * 16 + l16;
    #pragma unroll
    for (int mi = 0; mi < 4; ++mi) {
      f32x4 v = acc[mi][ni];
      int row0 = brow + wr * 64 + mi * 16 + lq * 4;
      #pragma unroll
      for (int j = 0; j < 4; ++j)
        Cz[(size_t)(row0 + j) * CATN + col] = f2bf(v[j]);
    }
  }
}

// ---- 256^2 8-phase GEMM with READ ROTATION (R7-proven core, reverted) ----
// + 2D XCD chunking (R5-proven: FETCH 557->205 MB).
// 8 waves (2M x 4N), BK=64, double-buffered LDS (128 KiB), full 3-bit swizzle
// (elem' = elem ^ ((row&7)<<3); linear LDS dest + inverse-swizzled global src).
// Per tile t (buf=t&1):
//  P1: stage Ah0(t+1); bar; lgkm0[waits R1 from prev P4]; {rd B-hi | MFMA AloxBlo}; bar
//  P2: stage Ah1(t+1); bar; lgkm0[waits B-hi];           {rd A-hi | MFMA AloxBhi}; bar
//  P3: stage Bh0(t+2); bar; lgkm0[waits A-hi];           {        MFMA AhixBhi}; bar
//  P4: stage Bh1(t+2); vmcnt(4); bar;                    {rd R1(t+1) | MFMA AhixBlo}; bar
__global__ __launch_bounds__(512, 2)
void gemm256_kernel(const ushort* __restrict__ A, const ushort* __restrict__ Bm,
                    float* __restrict__ C, const float* __restrict__ bias)
{
  __shared__ ushort lds[2][2][2][8192];   // [buf][mat 0=A 1=B][half][128*64]
  const int tid = threadIdx.x;
  const int wid = tid >> 6, l = tid & 63;
  const int wr = wid >> 2, wc = wid & 3;
  const int l16 = l & 15, lq = l >> 4;
  const int rxor = (l16 & 7) << 3;             // read-side elem XOR (row&7)<<3

  // XCD-aware 2D chunking: 512 blocks = 8 XCDs x 64; each XCD an 8x8 chunk.
  const int xcd = (int)blockIdx.x & 7, q = (int)blockIdx.x >> 3;
  const int brow = ((xcd >> 1) * 8 + (q >> 3)) * 256;
  const int bcol = ((xcd & 1) * 8 + (q & 7)) * 256;

  // staging: linear LDS dest; global source col pre-swizzled by dest row&7
  const int srow = tid >> 3;
  const int scol = (((tid & 7) ^ ((tid >> 3) & 7)) << 3);

#define STAGE(buf_, mat_, half_, kt_) do {                                        \
    const ushort* _s = (mat_) ? Bm : A;                                           \
    int _rb = ((mat_) ? bcol : brow) + (half_) * 128 + srow;                      \
    ushort* _d = &lds[(buf_)][(mat_)][(half_)][wid * 512];                        \
    _Pragma("unroll")                                                             \
    for (int _c = 0; _c < 2; ++_c) {                                              \
      const ushort* _g = _s + (size_t)(_rb + _c * 64) * KEXT + (kt_) * 64 + scol; \
      __builtin_amdgcn_global_load_lds(                                           \
          (const __attribute__((address_space(1))) void*)_g,                      \
          (__attribute__((address_space(3))) void*)(_d + _c * 4096), 16, 0, 0);   \
    } } while (0)

#define LDA_FRAG(buf_, mi_, ks_) \
  (*reinterpret_cast<const bf16x8*>(&lds[(buf_)][0][wr][((mi_) * 16 + l16) * 64 + (((ks_) * 32 + lq * 8) ^ rxor)]))
#define LDB_FRAG(buf_, ni_, ks_) \
  (*reinterpret_cast<const bf16x8*>(&lds[(buf_)][1][wc >> 1][((wc & 1) * 64 + (ni_) * 16 + l16) * 64 + (((ks_) * 32 + lq * 8) ^ rxor)]))

#define RD_ALO(buf_, dst_) \
    _Pragma("unroll") for (int mi = 0; mi < 4; ++mi) \
      _Pragma("unroll") for (int ks = 0; ks < 2; ++ks) dst_[mi][ks] = LDA_FRAG(buf_, mi, ks);
#define RD_BLO(buf_, dst_) \
    _Pragma("unroll") for (int ni = 0; ni < 2; ++ni) \
      _Pragma("unroll") for (int ks = 0; ks < 2; ++ks) dst_[ni][ks] = LDB_FRAG(buf_, ni, ks);

#define MFMA_Q(accm0_, accn0_, a_, b_) \
    _Pragma("unroll") for (int mi = 0; mi < 4; ++mi) \
      _Pragma("unroll") for (int ni = 0; ni < 2; ++ni) \
        _Pragma("unroll") for (int ks = 0; ks < 2; ++ks) \
          acc[(accm0_) + mi][(accn0_) + ni] = __builtin_amdgcn_mfma_f32_16x16x32_bf16( \
              a_[mi][ks], b_[ni][ks], acc[(accm0_) + mi][(accn0_) + ni], 0, 0, 0);

#define TILE(t_, buf_, aIn_, b0In_, aOut_, b0Out_) do {                           \
    bf16x8 b1[2][2], aHi[4][2];                                                   \
    const int ktA = ((t_) + 1 < NTK) ? (t_) + 1 : NTK - 1;                        \
    const int ktB = ((t_) + 2 < NTK) ? (t_) + 2 : NTK - 1;                        \
    /* P1 */                                                                      \
    STAGE(buf_ ^ 1, 0, 0, ktA);                                                   \
    __builtin_amdgcn_s_barrier();                                                 \
    asm volatile("s_waitcnt lgkmcnt(0)" ::: "memory");                            \
    __builtin_amdgcn_s_setprio(1);                                                \
    _Pragma("unroll") for (int ni = 0; ni < 2; ++ni)                              \
      _Pragma("unroll") for (int ks = 0; ks < 2; ++ks)                            \
        b1[ni][ks] = LDB_FRAG(buf_, ni + 2, ks);                                  \
    MFMA_Q(0, 0, aIn_, b0In_);                                                    \
    __builtin_amdgcn_s_setprio(0);                                                \
    __builtin_amdgcn_s_barrier();                                                 \
    /* P2 */                                                                      \
    STAGE(buf_ ^ 1, 0, 1, ktA);                                                   \
    __builtin_amdgcn_s_barrier();                                                 \
    asm volatile("s_waitcnt lgkmcnt(0)" ::: "memory");                            \
    __builtin_amdgcn_s_setprio(1);                                                \
    _Pragma("unroll") for (int mi = 0; mi < 4; ++mi)                              \
      _Pragma("unroll") for (int ks = 0; ks < 2; ++ks)                            \
        aHi[mi][ks] = LDA_FRAG(buf_, mi + 4, ks);                                 \
    MFMA_Q(0, 2, aIn_, b1);                                                       \
    __builtin_amdgcn_s_setprio(0);                                                \
    __builtin_amdgcn_s_barrier();                                                 \
    /* P3 */                                                                      \
    STAGE(buf_, 1, 0, ktB);                                                       \
    __builtin_amdgcn_s_barrier();                                                 \
    asm volatile("s_waitcnt lgkmcnt(0)" ::: "memory");                            \
    __builtin_amdgcn_s_setprio(1);                                                \
    MFMA_Q(4, 2, aHi, b1);                                                        \
    __builtin_amdgcn_s_setprio(0);                                                \
    __builtin_amdgcn_s_barrier();                                                 \
    /* P4 */                                                                      \
    STAGE(buf_, 1, 1, ktB);                                                       \
    asm volatile("s_waitcnt vmcnt(4)" ::: "memory");                              \
    __builtin_amdgcn_s_barrier();                                                 \
    __builtin_amdgcn_s_setprio(1);                                                \
    RD_ALO(buf_ ^ 1, aOut_);                                                      \
    RD_BLO(buf_ ^ 1, b0Out_);                                                     \
    MFMA_Q(4, 0, aHi, b0In_);                                                     \
    __builtin_amdgcn_s_setprio(0);                                                \
    __builtin_amdgcn_s_barrier();                                                 \
  } while (0)

  f32x4 acc[8][4] = {};
  bf16x8 aA[4][2], b0A[2][2], aB[4][2], b0B[2][2];

  // prologue: tile 0 complete + B(1); leave B(1) in flight, then pre-read R1(0)
  STAGE(0, 0, 0, 0); STAGE(0, 0, 1, 0);
  STAGE(0, 1, 0, 0); STAGE(0, 1, 1, 0);
  STAGE(1, 1, 0, 1); STAGE(1, 1, 1, 1);
  asm volatile("s_waitcnt vmcnt(4)" ::: "memory");
  __builtin_amdgcn_s_barrier();
  RD_ALO(0, aA);
  RD_BLO(0, b0A);

  #pragma unroll 1
  for (int tp = 0; tp < NTK / 2; ++tp) {
    TILE(2 * tp,     0, aA, b0A, aB, b0B);
    TILE(2 * tp + 1, 1, aB, b0B, aA, b0A);
  }

  asm volatile("s_waitcnt vmcnt(0) lgkmcnt(0)" ::: "memory");

  // epilogue: C/D layout col=l&15, row=(l>>4)*4+j (m89-verified)
  #pragma unroll
  for (int ni = 0; ni < 4; ++ni) {
    int col = bcol + wc * 64 + ni * 16 + l16;
    float bs = bias[col];
    #pragma unroll
    for (int mi = 0; mi < 8; ++mi) {
      int row0 = brow + wr * 128 + mi * 16 + lq * 4;
      #pragma unroll
      for (int j = 0; j < 4; ++j)
        C[(size_t)(row0 + j) * D_OUT + col] = acc[mi][ni][j] + bs;
    }
  }
#undef STAGE
#undef LDA_FRAG
#undef LDB_FRAG
#undef RD_ALO
#undef RD_BLO
#undef MFMA_Q
#undef TILE
}

extern "C" void kernel_launch(void* const* d_in, const int* in_sizes, int n_in,
                              void* d_out, int out_size, void* d_ws, size_t ws_size,
                              hipStream_t stream) {
  const float* x      = (const float*)d_in[0];
  const float* weight = (const float*)d_in[1];
  const float* bias   = (const float*)d_in[2];
  const float* rV     = (const float*)d_in[3];
  const float* rU     = (const float*)d_in[4];
  const float* rW     = (const float*)d_in[5];
  const float* expA   = (const float*)d_in[6];
  const float* expB   = (const float*)d_in[7];
  float* out = (float*)d_out;

  // workspace: x_ext[8192][4224], w_ext[4096][4224], cat[384][4096],
  // P[2][8192][384] bf16 split-K partials  (total ~119.5 MB, same as R2-R9)
  ushort* xe  = (ushort*)d_ws;
  ushort* we  = xe  + (size_t)M_TOT * KEXT;
  ushort* cat = we  + (size_t)D_OUT * KEXT;
  ushort* P   = cat + (size_t)CATN * D_IN;

  // x + weight -> bf16 strided  (one launch, grid exact)
  conv_xw_kernel<<<dim3((NX4 + NW4) / 256), 256, 0, stream>>>(x, weight, xe, we);

  // rV/rU/expA/expB preps (one launch)
  prep_small_kernel<<<dim3(5120), 256, 0, stream>>>(rV, rU, expA, expB, cat, we);

  // P[z] = x @ Cat^T partials   [2][8192, 384], split-K=2, XCD-grouped
  gemm128_kernel<<<dim3(384), 256, 0, stream>>>(xe, cat, P);

  // weighted lora-down -> x_ext cols 4096..4223
  gate_kernel<<<dim3(M_TOT / 4), 256, 0, stream>>>(P, rW, xe + D_IN);

  // out = x_ext @ w_ext^T + bias   [8192, 4096], K = 4224
  gemm256_kernel<<<dim3((D_OUT / 256) * (M_TOT / 256)), 512, 0, stream>>>(xe, we, out, bias);
}

// Round 11
// 340.529 us; speedup vs baseline: 1.1654x; 1.0146x over previous
//
#include <hip/hip_runtime.h>
#include <hip/hip_bf16.h>

// Problem constants
#define M_TOT   8192      // B*N tokens
#define D_IN    4096
#define D_OUT   4096
#define N_E     8
#define N_R     16
#define D_ATT   128
#define ER      128       // N_E*N_R
#define CATN    384       // 2*D_ATT + ER
#define KEXT    4224      // D_IN + ER (padded K for unified GEMM)
#define NTK     66        // KEXT/64 K-tiles (even)
#define NX4     (8388608L)  // M_TOT*D_IN/4
#define NW4     (4194304L)  // D_OUT*D_IN/4
#define NCONVB  49152       // (NX4+NW4)/256 blocks for the conv part

typedef __attribute__((ext_vector_type(8)))  __bf16 bf16x8;
typedef __attribute__((ext_vector_type(4)))  float  f32x4;

__device__ __forceinline__ ushort f2bf(float f) {
  union { float f; unsigned u; } v; v.f = f;
  unsigned r = (v.u + 0x7fffu + ((v.u >> 16) & 1u)) >> 16;
  return (ushort)r;
}
__device__ __forceinline__ float bf2f(ushort u) {
  union { unsigned u; float f; } v; v.u = ((unsigned)u) << 16;
  return v.f;
}

// ---- ONE prep kernel: x+w fp32->bf16 strided (bulk), rV/rU -> cat rows
// 0..255, expA -> cat rows 256..383, expB -> we cols 4096..  ----
__global__ void prep_kernel(const float* __restrict__ x, const float* __restrict__ w,
                            const float* __restrict__ rV, const float* __restrict__ rU,
                            const float* __restrict__ expA, const float* __restrict__ expB,
                            ushort* __restrict__ xe, ushort* __restrict__ we,
                            ushort* __restrict__ cat) {
  int b = blockIdx.x;
  if (b < NCONVB) {                     // x + weight conversion, float4 granules
    long i = (long)b * 256 + threadIdx.x;
    const float* src; ushort* dst; long j;
    if (i < NX4) { src = x; dst = xe; j = i; }
    else         { src = w; dst = we; j = i - NX4; }
    const float4 a = reinterpret_cast<const float4*>(src)[j];
    ushort4 r; r.x = f2bf(a.x); r.y = f2bf(a.y); r.z = f2bf(a.z); r.w = f2bf(a.w);
    long row = j >> 10, c4 = (j & 1023) << 2;
    *reinterpret_cast<ushort4*>(dst + row * KEXT + c4) = r;
  } else if (b < NCONVB + 1024) {       // rV (512) + rU (512), float4 elems
    int bb = b - NCONVB;
    const float* src = (bb < 512) ? rV : rU;
    ushort* dst = cat + ((bb < 512) ? 0 : (size_t)D_ATT * D_IN);
    int i = (bb & 511) * 256 + threadIdx.x;         // < 131072
    const float4 a = reinterpret_cast<const float4*>(src)[i];
    ushort4 r; r.x = f2bf(a.x); r.y = f2bf(a.y); r.z = f2bf(a.z); r.w = f2bf(a.w);
    reinterpret_cast<ushort4*>(dst)[i] = r;
  } else if (b < NCONVB + 3072) {       // catA scatter
    int idx = (b - NCONVB - 1024) * 256 + threadIdx.x;   // < 524288
    int j = idx >> 12, d = idx & 4095;
    int e = j >> 4, r = j & 15;
    cat[(size_t)(2 * D_ATT + j) * D_IN + d] = f2bf(expA[((size_t)e * D_IN + d) * N_R + r]);
  } else {                              // bt transpose
    int idx = (b - NCONVB - 3072) * 256 + threadIdx.x;   // < 524288
    int j = idx >> 12, o = idx & 4095;                   // coalesced read of expB row j
    we[(size_t)o * KEXT + D_IN + j] = f2bf(expB[(size_t)j * D_OUT + o]);
  }
}

// ---- gating over split-K partials P[2][M][CATN] (bf16):
// P[*][m,0:128]=xV^T, [128:256]=xU^T, [256:384]=lora_down; writes weighted
// lora-down into x_ext cols 4096..4223 (stride KEXT)
__global__ void gate_kernel(const ushort* __restrict__ P, const float* __restrict__ rW,
                            ushort* __restrict__ wtd) {
  int token = blockIdx.x * 4 + (threadIdx.x >> 6);
  int l = threadIdx.x & 63;
  const ushort* p0 = P + (size_t)token * CATN;
  const ushort* p1 = p0 + (size_t)M_TOT * CATN;
  float v0 = tanhf(bf2f(p0[l])      + bf2f(p1[l]));
  float v1 = tanhf(bf2f(p0[l + 64]) + bf2f(p1[l + 64]));
  float u0 = 1.f / (1.f + __expf(-(bf2f(p0[D_ATT + l])      + bf2f(p1[D_ATT + l]))));
  float u1 = 1.f / (1.f + __expf(-(bf2f(p0[D_ATT + l + 64]) + bf2f(p1[D_ATT + l + 64]))));
  float g0 = v0 * u0, g1 = v1 * u1;
  float rw[8];
  #pragma unroll
  for (int e = 0; e < 8; ++e) {
    float s = g0 * rW[e * D_ATT + l] + g1 * rW[e * D_ATT + l + 64];
    #pragma unroll
    for (int off = 32; off > 0; off >>= 1) s += __shfl_xor(s, off);
    rw[e] = 1.f / (1.f + __expf(-s));
  }
  int q = l >> 4;  // expert index within half (static-select to avoid scratch)
  float rw_a = (q == 0) ? rw[0] : (q == 1) ? rw[1] : (q == 2) ? rw[2] : rw[3];
  float rw_b = (q == 0) ? rw[4] : (q == 1) ? rw[5] : (q == 2) ? rw[6] : rw[7];
  float lo_a = bf2f(p0[2 * D_ATT + l])      + bf2f(p1[2 * D_ATT + l]);
  float lo_b = bf2f(p0[2 * D_ATT + l + 64]) + bf2f(p1[2 * D_ATT + l + 64]);
  wtd[(size_t)token * KEXT + l]      = f2bf(lo_a * rw_a);
  wtd[(size_t)token * KEXT + l + 64] = f2bf(lo_b * rw_b);
}

// ---- 128^2 m97-structure router GEMM, split-K=2 (R7-exact version) ----
// P[z] = x_ext[:, z*2048:(z+1)*2048] @ cat[:, same]^T  (bf16 partials)
// launch_bounds(256,4): 4 blocks/CU co-resident (LDS 4x32KB=128<=160, VGPR 60)
// -- the 2-barrier m97 structure relies on multi-block TLP (m114).
__global__ __launch_bounds__(256, 4)
void gemm128_kernel(const ushort* __restrict__ A, const ushort* __restrict__ Bm,
                    ushort* __restrict__ C)
{
  __shared__ ushort As[128 * 64];
  __shared__ ushort Bs[128 * 64];
  const int tid = threadIdx.x;
  const int w = tid >> 6, l = tid & 63;
  const int wr = w >> 1, wc = w & 1;
  const int l16 = l & 15, lq = l >> 4;
  const int brow = blockIdx.y * 128;
  const int bcol = blockIdx.x * 128;
  const int kt0 = (int)blockIdx.z << 5;           // 32 K-tiles per split

  f32x4 acc[4][4] = {};

  for (int kt = kt0; kt < kt0 + 32; ++kt) {
    int k0 = kt << 6;
    #pragma unroll
    for (int c = 0; c < 4; ++c) {
      int rloc = w * 32 + c * 8;
      int rl = rloc + (l >> 3);
      int kk = k0 + (l & 7) * 8;
      const ushort* ga = A  + (size_t)(brow + rl) * KEXT + kk;
      const ushort* gb = Bm + (size_t)(bcol + rl) * D_IN + kk;
      __builtin_amdgcn_global_load_lds((const __attribute__((address_space(1))) void*)ga,
                                       (__attribute__((address_space(3))) void*)(As + rloc * 64),
                                       16, 0, 0);
      __builtin_amdgcn_global_load_lds((const __attribute__((address_space(1))) void*)gb,
                                       (__attribute__((address_space(3))) void*)(Bs + rloc * 64),
                                       16, 0, 0);
    }
    __syncthreads();

    #pragma unroll
    for (int ks = 0; ks < 2; ++ks) {
      bf16x8 af[4], bfv[4];
      #pragma unroll
      for (int mi = 0; mi < 4; ++mi)
        af[mi] = *reinterpret_cast<const bf16x8*>(As + (wr * 64 + mi * 16 + l16) * 64 + ks * 32 + lq * 8);
      #pragma unroll
      for (int ni = 0; ni < 4; ++ni)
        bfv[ni] = *reinterpret_cast<const bf16x8*>(Bs + (wc * 64 + ni * 16 + l16) * 64 + ks * 32 + lq * 8);
      #pragma unroll
      for (int mi = 0; mi < 4; ++mi)
        #pragma unroll
        for (int ni = 0; ni < 4; ++ni)
          acc[mi][ni] = __builtin_amdgcn_mfma_f32_16x16x32_bf16(af[mi], bfv[ni], acc[mi][ni], 0, 0, 0);
    }
    __syncthreads();
  }

  ushort* Cz = C + (size_t)blockIdx.z * M_TOT * CATN;
  #pragma unroll
  for (int ni = 0; ni < 4; ++ni) {
    int col = bcol + wc * 64 + ni * 16 + l16;
    #pragma unroll
    for (int mi = 0; mi < 4; ++mi) {
      f32x4 v = acc[mi][ni];
      int row0 = brow + wr * 64 + mi * 16 + lq * 4;
      #pragma unroll
      for (int j = 0; j < 4; ++j)
        Cz[(size_t)(row0 + j) * CATN + col] = f2bf(v[j]);
    }
  }
}

// ---- 256^2 8-phase GEMM with READ ROTATION (R7-proven core, frozen) ----
// + 2D XCD chunking (R5-proven: FETCH 557->205 MB).
// 8 waves (2M x 4N), BK=64, double-buffered LDS (128 KiB), full 3-bit swizzle
// (elem' = elem ^ ((row&7)<<3); linear LDS dest + inverse-swizzled global src).
// Per tile t (buf=t&1):
//  P1: stage Ah0(t+1); bar; lgkm0[waits R1 from prev P4]; {rd B-hi | MFMA AloxBlo}; bar
//  P2: stage Ah1(t+1); bar; lgkm0[waits B-hi];           {rd A-hi | MFMA AloxBhi}; bar
//  P3: stage Bh0(t+2); bar; lgkm0[waits A-hi];           {        MFMA AhixBhi}; bar
//  P4: stage Bh1(t+2); vmcnt(4); bar;                    {rd R1(t+1) | MFMA AhixBlo}; bar
__global__ __launch_bounds__(512, 2)
void gemm256_kernel(const ushort* __restrict__ A, const ushort* __restrict__ Bm,
                    float* __restrict__ C, const float* __restrict__ bias)
{
  __shared__ ushort lds[2][2][2][8192];   // [buf][mat 0=A 1=B][half][128*64]
  const int tid = threadIdx.x;
  const int wid = tid >> 6, l = tid & 63;
  const int wr = wid >> 2, wc = wid & 3;
  const int l16 = l & 15, lq = l >> 4;
  const int rxor = (l16 & 7) << 3;             // read-side elem XOR (row&7)<<3

  // XCD-aware 2D chunking: 512 blocks = 8 XCDs x 64; each XCD an 8x8 chunk.
  const int xcd = (int)blockIdx.x & 7, q = (int)blockIdx.x >> 3;
  const int brow = ((xcd >> 1) * 8 + (q >> 3)) * 256;
  const int bcol = ((xcd & 1) * 8 + (q & 7)) * 256;

  // staging: linear LDS dest; global source col pre-swizzled by dest row&7
  const int srow = tid >> 3;
  const int scol = (((tid & 7) ^ ((tid >> 3) & 7)) << 3);

#define STAGE(buf_, mat_, half_, kt_) do {                                        \
    const ushort* _s = (mat_) ? Bm : A;                                           \
    int _rb = ((mat_) ? bcol : brow) + (half_) * 128 + srow;                      \
    ushort* _d = &lds[(buf_)][(mat_)][(half_)][wid * 512];                        \
    _Pragma("unroll")                                                             \
    for (int _c = 0; _c < 2; ++_c) {                                              \
      const ushort* _g = _s + (size_t)(_rb + _c * 64) * KEXT + (kt_) * 64 + scol; \
      __builtin_amdgcn_global_load_lds(                                           \
          (const __attribute__((address_space(1))) void*)_g,                      \
          (__attribute__((address_space(3))) void*)(_d + _c * 4096), 16, 0, 0);   \
    } } while (0)

#define LDA_FRAG(buf_, mi_, ks_) \
  (*reinterpret_cast<const bf16x8*>(&lds[(buf_)][0][wr][((mi_) * 16 + l16) * 64 + (((ks_) * 32 + lq * 8) ^ rxor)]))
#define LDB_FRAG(buf_, ni_, ks_) \
  (*reinterpret_cast<const bf16x8*>(&lds[(buf_)][1][wc >> 1][((wc & 1) * 64 + (ni_) * 16 + l16) * 64 + (((ks_) * 32 + lq * 8) ^ rxor)]))

#define RD_ALO(buf_, dst_) \
    _Pragma("unroll") for (int mi = 0; mi < 4; ++mi) \
      _Pragma("unroll") for (int ks = 0; ks < 2; ++ks) dst_[mi][ks] = LDA_FRAG(buf_, mi, ks);
#define RD_BLO(buf_, dst_) \
    _Pragma("unroll") for (int ni = 0; ni < 2; ++ni) \
      _Pragma("unroll") for (int ks = 0; ks < 2; ++ks) dst_[ni][ks] = LDB_FRAG(buf_, ni, ks);

#define MFMA_Q(accm0_, accn0_, a_, b_) \
    _Pragma("unroll") for (int mi = 0; mi < 4; ++mi) \
      _Pragma("unroll") for (int ni = 0; ni < 2; ++ni) \
        _Pragma("unroll") for (int ks = 0; ks < 2; ++ks) \
          acc[(accm0_) + mi][(accn0_) + ni] = __builtin_amdgcn_mfma_f32_16x16x32_bf16( \
              a_[mi][ks], b_[ni][ks], acc[(accm0_) + mi][(accn0_) + ni], 0, 0, 0);

#define TILE(t_, buf_, aIn_, b0In_, aOut_, b0Out_) do {                           \
    bf16x8 b1[2][2], aHi[4][2];                                                   \
    const int ktA = ((t_) + 1 < NTK) ? (t_) + 1 : NTK - 1;                        \
    const int ktB = ((t_) + 2 < NTK) ? (t_) + 2 : NTK - 1;                        \
    /* P1 */                                                                      \
    STAGE(buf_ ^ 1, 0, 0, ktA);                                                   \
    __builtin_amdgcn_s_barrier();                                                 \
    asm volatile("s_waitcnt lgkmcnt(0)" ::: "memory");                            \
    __builtin_amdgcn_s_setprio(1);                                                \
    _Pragma("unroll") for (int ni = 0; ni < 2; ++ni)                              \
      _Pragma("unroll") for (int ks = 0; ks < 2; ++ks)                            \
        b1[ni][ks] = LDB_FRAG(buf_, ni + 2, ks);                                  \
    MFMA_Q(0, 0, aIn_, b0In_);                                                    \
    __builtin_amdgcn_s_setprio(0);                                                \
    __builtin_amdgcn_s_barrier();                                                 \
    /* P2 */                                                                      \
    STAGE(buf_ ^ 1, 0, 1, ktA);                                                   \
    __builtin_amdgcn_s_barrier();                                                 \
    asm volatile("s_waitcnt lgkmcnt(0)" ::: "memory");                            \
    __builtin_amdgcn_s_setprio(1);                                                \
    _Pragma("unroll") for (int mi = 0; mi < 4; ++mi)                              \
      _Pragma("unroll") for (int ks = 0; ks < 2; ++ks)                            \
        aHi[mi][ks] = LDA_FRAG(buf_, mi + 4, ks);                                 \
    MFMA_Q(0, 2, aIn_, b1);                                                       \
    __builtin_amdgcn_s_setprio(0);                                                \
    __builtin_amdgcn_s_barrier();                                                 \
    /* P3 */                                                                      \
    STAGE(buf_, 1, 0, ktB);                                                       \
    __builtin_amdgcn_s_barrier();                                                 \
    asm volatile("s_waitcnt lgkmcnt(0)" ::: "memory");                            \
    __builtin_amdgcn_s_setprio(1);                                                \
    MFMA_Q(4, 2, aHi, b1);                                                        \
    __builtin_amdgcn_s_setprio(0);                                                \
    __builtin_amdgcn_s_barrier();                                                 \
    /* P4 */                                                                      \
    STAGE(buf_, 1, 1, ktB);                                                       \
    asm volatile("s_waitcnt vmcnt(4)" ::: "memory");                              \
    __builtin_amdgcn_s_barrier();                                                 \
    __builtin_amdgcn_s_setprio(1);                                                \
    RD_ALO(buf_ ^ 1, aOut_);                                                      \
    RD_BLO(buf_ ^ 1, b0Out_);                                                     \
    MFMA_Q(4, 0, aHi, b0In_);                                                     \
    __builtin_amdgcn_s_setprio(0);                                                \
    __builtin_amdgcn_s_barrier();                                                 \
  } while (0)

  f32x4 acc[8][4] = {};
  bf16x8 aA[4][2], b0A[2][2], aB[4][2], b0B[2][2];

  // prologue: tile 0 complete + B(1); leave B(1) in flight, then pre-read R1(0)
  STAGE(0, 0, 0, 0); STAGE(0, 0, 1, 0);
  STAGE(0, 1, 0, 0); STAGE(0, 1, 1, 0);
  STAGE(1, 1, 0, 1); STAGE(1, 1, 1, 1);
  asm volatile("s_waitcnt vmcnt(4)" ::: "memory");
  __builtin_amdgcn_s_barrier();
  RD_ALO(0, aA);
  RD_BLO(0, b0A);

  #pragma unroll 1
  for (int tp = 0; tp < NTK / 2; ++tp) {
    TILE(2 * tp,     0, aA, b0A, aB, b0B);
    TILE(2 * tp + 1, 1, aB, b0B, aA, b0A);
  }

  asm volatile("s_waitcnt vmcnt(0) lgkmcnt(0)" ::: "memory");

  // epilogue: C/D layout col=l&15, row=(l>>4)*4+j (m89-verified)
  #pragma unroll
  for (int ni = 0; ni < 4; ++ni) {
    int col = bcol + wc * 64 + ni * 16 + l16;
    float bs = bias[col];
    #pragma unroll
    for (int mi = 0; mi < 8; ++mi) {
      int row0 = brow + wr * 128 + mi * 16 + lq * 4;
      #pragma unroll
      for (int j = 0; j < 4; ++j)
        C[(size_t)(row0 + j) * D_OUT + col] = acc[mi][ni][j] + bs;
    }
  }
#undef STAGE
#undef LDA_FRAG
#undef LDB_FRAG
#undef RD_ALO
#undef RD_BLO
#undef MFMA_Q
#undef TILE
}

extern "C" void kernel_launch(void* const* d_in, const int* in_sizes, int n_in,
                              void* d_out, int out_size, void* d_ws, size_t ws_size,
                              hipStream_t stream) {
  const float* x      = (const float*)d_in[0];
  const float* weight = (const float*)d_in[1];
  const float* bias   = (const float*)d_in[2];
  const float* rV     = (const float*)d_in[3];
  const float* rU     = (const float*)d_in[4];
  const float* rW     = (const float*)d_in[5];
  const float* expA   = (const float*)d_in[6];
  const float* expB   = (const float*)d_in[7];
  float* out = (float*)d_out;

  // workspace: x_ext[8192][4224], w_ext[4096][4224], cat[384][4096],
  // P[2][8192][384] bf16 split-K partials  (total ~114.7 MB, same as R2-R10)
  ushort* xe  = (ushort*)d_ws;
  ushort* we  = xe  + (size_t)M_TOT * KEXT;
  ushort* cat = we  + (size_t)D_OUT * KEXT;
  ushort* P   = cat + (size_t)CATN * D_IN;

  // ALL conversions + preps in one launch
  prep_kernel<<<dim3(NCONVB + 1024 + 2048 + 2048), 256, 0, stream>>>(
      x, weight, rV, rU, expA, expB, xe, we, cat);

  // P[z] = x @ Cat^T partials   [2][8192, 384], split-K=2  (R7-exact)
  gemm128_kernel<<<dim3(CATN / 128, M_TOT / 128, 2), 256, 0, stream>>>(xe, cat, P);

  // weighted lora-down -> x_ext cols 4096..4223
  gate_kernel<<<dim3(M_TOT / 4), 256, 0, stream>>>(P, rW, xe + D_IN);

  // out = x_ext @ w_ext^T + bias   [8192, 4096], K = 4224
  gemm256_kernel<<<dim3((D_OUT / 256) * (M_TOT / 256)), 512, 0, stream>>>(xe, we, out, bias);
}